// Round 12
// baseline (261.612 us; speedup 1.0000x reference)
//
#include <hip/hip_runtime.h>
#include <hip/hip_bf16.h>
#include <math.h>

// ChordAwareTransformer bf16-MFMA pipeline, round 18.
// R18 = R17 + attn: (a) 4 barrier domains/CU: ATQ=64, 4 waves/block, grid
// (32,32)=1024 blocks = exactly 4 x 40KB-LDS blocks per CU (R17 grid was
// 512 = only 2 domains; the serial QK->softmax->PV chain left 19% idle).
// Per-wave per-kt code IDENTICAL to R17; staging = 5 slots/wave (2 Kseg0,
// 1 Kseg1, 2 V — uniform). (b) l via ones-MFMA: ol=mfma(pA,ones,ol) (2
// extra MFMA/kt on the 31%-busy matrix pipe) replaces 16 VALU adds/kt;
// epilogue invr[r]=1/ol[r] in-lane (no shfls). l sums bf16 P — consistent
// with O=P@V which uses the same bf16 P.
// R17: unrolled x2 K-loops, literal buffer offsets; R16: prep split;
// R15: P-in-register permlane swaps; R14: gemm0 XCD swizzle + transpose
// epilogue; R13: rank-12 d=96 refactor.
// MFMA layouts (HW-verified): A[m=lane&15][k=quad*8+j], B[k][n=lane&15],
// C/D row=quad*4+reg, col=lane&15.

#define D_    1024
#define H_    16
#define B_    2
#define S_    2048
#define M_    (B_*S_)
#define QROW_ 1536          // Q96/K96 row stride in shorts (16 heads * 96)

#define QSCALE_ (1.44269504f / 24.0f)   // log2e * (1/sqrt(64)) / 3

#if __has_builtin(__builtin_amdgcn_exp2f)
#define EXP2(x) __builtin_amdgcn_exp2f(x)
#else
#define EXP2(x) exp2f(x)
#endif

typedef __attribute__((ext_vector_type(8))) short s16x8;
typedef __attribute__((ext_vector_type(4))) float f32x4;

__device__ __forceinline__ unsigned short f2bf(float f) {
    unsigned u = __builtin_bit_cast(unsigned, f);
    u += 0x7fff + ((u >> 16) & 1);          // RNE
    return (unsigned short)(u >> 16);
}
__device__ __forceinline__ unsigned pk2(float a, float b) {
    __hip_bfloat162 h = __float22bfloat162_rn(float2{a, b});
    unsigned r;
    __builtin_memcpy(&r, &h, 4);
    return r;
}

#define GLDS16(gp, lp) \
    __builtin_amdgcn_global_load_lds((const __attribute__((address_space(1))) void*)(gp), \
                                     (__attribute__((address_space(3))) void*)(lp), 16, 0, 0)

// ---------------------------------------------------------------- prep kernels
struct PrepArgs {
    const float* x;
    const float* pitch_pc; const float* bass_pc;
    const float* Wc; const float* Wb;
    const float* Whq; const float* bhq;
    const float* Wvq; const float* bvq;
    const float* wsrc[4]; unsigned short* wdst[4];   // Wpq,Wk,Wv,Wo
    const float* bsrc[3]; float* bias5;              // bpq,bk,bv
    unsigned short* Whcvt;                           // 384 x 1024 (Bt rows 3072..3455)
    unsigned short* xb; unsigned short* Q96; unsigned short* K96;
};

// ---- cvt_x: fp32 -> bf16, pure streaming copy (low VGPR, no LDS)
__global__ __launch_bounds__(256) void cvt_kernel(PrepArgs a) {
    int i = (blockIdx.x * 256 + threadIdx.x) * 4;
    float4 v = *(const float4*)(a.x + i);
    uint2 o = {pk2(v.x, v.y), pk2(v.z, v.w)};
    *(uint2*)(a.xb + i) = o;
}

// ---- wtrans: 4 weights, 64x64 transpose tiles via LDS
__global__ __launch_bounds__(256) void wtrans_kernel(PrepArgs a) {
    __shared__ unsigned short t[64][72];
    int bx = blockIdx.x;
    const int tid = threadIdx.x;
    int z = bx >> 8, rem = bx & 255;
    const float* src = a.wsrc[z];
    unsigned short* dst = a.wdst[z];
    int k0 = (rem >> 4) * 64, n0 = (rem & 15) * 64;
    int r = tid >> 2, c0 = (tid & 3) * 16;
#pragma unroll
    for (int i = 0; i < 4; ++i) {
        float4 v = *(const float4*)(src + (size_t)(k0 + r) * 1024 + n0 + c0 + i * 4);
        ushort4 o = {f2bf(v.x), f2bf(v.y), f2bf(v.z), f2bf(v.w)};
        *(ushort4*)&t[r][c0 + i * 4] = o;
    }
    __syncthreads();
#pragma unroll
    for (int i = 0; i < 4; ++i) {
        ushort4 o = {t[c0 + i*4 + 0][r], t[c0 + i*4 + 1][r],
                     t[c0 + i*4 + 2][r], t[c0 + i*4 + 3][r]};
        *(ushort4*)(dst + (size_t)(n0 + r) * 1024 + k0 + c0 + i * 4) = o;
    }
}

// ---- misc: bpack (12) + fold (384, vectorized) + pcpack (256)
__global__ __launch_bounds__(256) void misc_kernel(PrepArgs a) {
    int bx = blockIdx.x;
    const int tid = threadIdx.x;

    if (bx < 12) {                         // ---- bpack (bpq,bk,bv)
        int i = bx * 256 + tid;
        a.bias5[i] = a.bsrc[i >> 10][i & 1023];
        return;
    }
    bx -= 12;
    if (bx < 384) {                        // ---- fold: Whcvt row j (Bt layout)
        int j = bx;
        int h = j / 24, r = j - h * 24;
        const float* src = (r < 12) ? a.Whq : a.Wvq;
        const float* pcw = (r < 12) ? a.Wc  : a.Wb;
        const float* bsr = (r < 12) ? a.bhq : a.bvq;
        int i = (r < 12) ? r : r - 12;
        int hb = h * 64;
        const float4* p4 = (const float4*)(pcw + (size_t)i * 1024 + hb);
        float4 pv[16];
#pragma unroll
        for (int d = 0; d < 16; ++d) pv[d] = p4[d];
#pragma unroll
        for (int ro = 0; ro < 4; ++ro) {
            int row = tid + ro * 256;
            const float4* s4 = (const float4*)(src + (size_t)row * 1024 + hb);
            float a0 = 0.f, a1 = 0.f, a2 = 0.f, a3 = 0.f;
#pragma unroll
            for (int d = 0; d < 16; d += 4) {
                float4 v0 = s4[d], v1 = s4[d+1], v2 = s4[d+2], v3 = s4[d+3];
                a0 = fmaf(v0.x, pv[d].x, fmaf(v0.y, pv[d].y,
                     fmaf(v0.z, pv[d].z, fmaf(v0.w, pv[d].w, a0))));
                a1 = fmaf(v1.x, pv[d+1].x, fmaf(v1.y, pv[d+1].y,
                     fmaf(v1.z, pv[d+1].z, fmaf(v1.w, pv[d+1].w, a1))));
                a2 = fmaf(v2.x, pv[d+2].x, fmaf(v2.y, pv[d+2].y,
                     fmaf(v2.z, pv[d+2].z, fmaf(v2.w, pv[d+2].w, a2))));
                a3 = fmaf(v3.x, pv[d+3].x, fmaf(v3.y, pv[d+3].y,
                     fmaf(v3.z, pv[d+3].z, fmaf(v3.w, pv[d+3].w, a3))));
            }
            a.Whcvt[(size_t)j * 1024 + row] = f2bf((a0 + a1) + (a2 + a3));
        }
        if (tid == 0) {
            float bacc = 0.f;
            for (int d = 0; d < 64; ++d)
                bacc = fmaf(bsr[hb + d], pcw[i * 1024 + hb + d], bacc);
            a.bias5[3072 + j] = bacc;
        }
        return;
    }
    bx -= 384;
    {                                      // ---- pcpack: K96 pc cols + pads; Q96 pads
        int idx = bx * 256 + tid;          // 65536 = M*H
        int m = idx >> 4, h = idx & 15;
        int s = m & (S_ - 1);
        unsigned short buf[32];
#pragma unroll
        for (int i = 0; i < 12; ++i) buf[i] = f2bf(a.pitch_pc[s * 12 + i]);
        buf[12] = buf[13] = buf[14] = buf[15] = 0;
#pragma unroll
        for (int i = 0; i < 12; ++i) buf[16 + i] = f2bf(a.bass_pc[s * 12 + i]);
        buf[28] = buf[29] = buf[30] = buf[31] = 0;
        unsigned short* kd = a.K96 + (size_t)m * QROW_ + h * 96 + 64;
#pragma unroll
        for (int i = 0; i < 4; ++i)
            *(uint4*)(kd + i * 8) = *(uint4*)&buf[i * 8];
        unsigned short* qd = a.Q96 + (size_t)m * QROW_ + h * 96 + 64;
        uint2 z = {0u, 0u};
        *(uint2*)(qd + 12) = z;            // cols 76..79
        *(uint2*)(qd + 28) = z;            // cols 92..95
    }
}

// ---------------------------------------------------------------- MFMA GEMM
// C[M x N] = A[M x 1024] @ Bt^T + bias.  BK=32, double-buffered, one barrier
// per K-tile; kt-loop unrolled x2 (literal buffer offsets 0/16384).
// XCD-swizzled block ids (nwg%8==0 both modes).
// MODE 0 (N=3456): wsel0 pitch_q*QS -> Q96; wsel1 k -> K96 (both via LDS
//   transpose epilogue, 128B row stores); wsel2 v -> Vt^T (uint2, coalesced);
//   wsel3 hq/vq*QS -> Q96 cols 64+/68+ (scalar, 3 tiles only).
// MODE 1: N=1024, fp32 out.
template<int MODE>
__global__ __launch_bounds__(256) void gemm_k(
    const unsigned short* __restrict__ A, const unsigned short* __restrict__ Bt,
    const float* __restrict__ bias, unsigned short* __restrict__ Qb,
    unsigned short* __restrict__ Kb, unsigned short* __restrict__ Vt,
    float* __restrict__ Cf)
{
    __shared__ __align__(16) unsigned char lds[32768];
    const int tid = threadIdx.x;
    const int wv = tid >> 6, lane = tid & 63;
    const int lq = lane & 15, quad = lane >> 4;
    const int wm = wv >> 1, wn = wv & 1;

    // XCD-aware swizzle: each XCD gets a contiguous chunk (nwg % 8 == 0)
    const unsigned bid = blockIdx.y * gridDim.x + blockIdx.x;
    const unsigned cpx = (gridDim.x * gridDim.y) >> 3;
    const unsigned swz = (bid & 7) * cpx + (bid >> 3);
    const int m0 = (int)(swz / gridDim.x) * 128;
    const int n0 = (int)(swz % gridDim.x) * 128;

    const int sr = lane >> 2;
    const int sc = (lane & 3) ^ ((lane >> 3) & 3);

    // staging source pointers (advance += 32 shorts per staged kt)
    const unsigned short* Asrc[2];
    const unsigned short* Bsrc[2];
    unsigned dla[2], dlb[2];
#pragma unroll
    for (int j = 0; j < 2; ++j) {
        int seg = wv * 2 + j;
        Asrc[j] = A + (size_t)(m0 + seg * 16 + sr) * 1024 + sc * 8;
        Bsrc[j] = Bt + (size_t)(n0 + seg * 16 + sr) * 1024 + sc * 8;
        dla[j] = seg * 1024;
        dlb[j] = 8192 + seg * 1024;
    }

    // loop-invariant LDS read pointers
    const unsigned char* ap[4];
    const unsigned char* bp4[4];
#pragma unroll
    for (int mi = 0; mi < 4; ++mi) {
        int row = wm * 64 + mi * 16 + lq;
        ap[mi] = lds + row * 64 + ((quad ^ ((row >> 1) & 3)) * 16);
    }
#pragma unroll
    for (int ni = 0; ni < 4; ++ni) {
        int row = wn * 64 + ni * 16 + lq;
        bp4[ni] = lds + 8192 + row * 64 + ((quad ^ ((row >> 1) & 3)) * 16);
    }

    f32x4 acc[4][4] = {};

#define GSTAGE(DSTOFF) do { \
    _Pragma("unroll") \
    for (int j = 0; j < 2; ++j) { \
        GLDS16(Asrc[j], lds + (dla[j] + (DSTOFF))); Asrc[j] += 32; \
        GLDS16(Bsrc[j], lds + (dlb[j] + (DSTOFF))); Bsrc[j] += 32; \
    } \
} while (0)

#define GTILE(CUROFF) do { \
    s16x8 aF[4], bF[4]; \
    _Pragma("unroll") \
    for (int mi = 0; mi < 4; ++mi) aF[mi] = *(const s16x8*)(ap[mi] + (CUROFF)); \
    _Pragma("unroll") \
    for (int ni = 0; ni < 4; ++ni) bF[ni] = *(const s16x8*)(bp4[ni] + (CUROFF)); \
    _Pragma("unroll") \
    for (int mi = 0; mi < 4; ++mi) \
        _Pragma("unroll") \
        for (int ni = 0; ni < 4; ++ni) \
            acc[mi][ni] = __builtin_amdgcn_mfma_f32_16x16x32_bf16( \
                aF[mi], bF[ni], acc[mi][ni], 0, 0, 0); \
} while (0)

    GSTAGE(0);                     // prologue: kt=0 -> buf0
    for (int i2 = 0; i2 < 16; ++i2) {
        __syncthreads();
        GSTAGE(16384);             // kt=2*i2+1 -> buf1
        GTILE(0);                  // compute kt=2*i2
        __syncthreads();
        if (i2 < 15) GSTAGE(0);    // kt=2*i2+2 -> buf0
        GTILE(16384);              // compute kt=2*i2+1
    }
#undef GSTAGE
#undef GTILE

    if (MODE == 0) {
        const int wsel = n0 >> 10;
        if (wsel <= 1) {
            // ---- LDS-transpose epilogue: C tile [128 m][128 n] bf16 in lds,
            // chunk pos = (col>>3) ^ (row&7); then 128B-contiguous row stores.
            const float sc2 = (wsel == 0) ? QSCALE_ : 1.0f;
            unsigned short* lt = (unsigned short*)lds;
            __syncthreads();   // all waves done reading staging bufs
#pragma unroll
            for (int ni = 0; ni < 4; ++ni) {
                int col = wn * 64 + ni * 16 + lq;
                float bv = bias[n0 + col];
#pragma unroll
                for (int mi = 0; mi < 4; ++mi) {
#pragma unroll
                    for (int r = 0; r < 4; ++r) {
                        int row = wm * 64 + mi * 16 + quad * 4 + r;
                        int pos = (col >> 3) ^ (row & 7);
                        lt[row * 128 + pos * 8 + (col & 7)] =
                            f2bf((acc[mi][ni][r] + bv) * sc2);
                    }
                }
            }
            __syncthreads();
            const int row = tid >> 1, seg = tid & 1;
            const int nl0 = n0 & 1023;
            unsigned short* dstp = (wsel == 0) ? Qb : Kb;
            unsigned short* dbase = dstp + (size_t)(m0 + row) * QROW_
                                    + (nl0 >> 6) * 96 + seg * 96;
#pragma unroll
            for (int i = 0; i < 8; ++i) {
                int c = seg * 8 + i;
                int pos = c ^ (row & 7);
                *(uint4*)(dbase + i * 8) = *(const uint4*)(lt + row * 128 + pos * 8);
            }
        } else if (wsel == 2) {            // v -> Vt^T (bf16 pairs, coalesced on m)
#pragma unroll
            for (int ni = 0; ni < 4; ++ni) {
                int n = n0 + wn * 64 + ni * 16 + lq;
                float bv = bias[n];
                int nl = n - 2048, h = nl >> 6, d = nl & 63;
#pragma unroll
                for (int mi = 0; mi < 4; ++mi) {
                    int mrow = m0 + wm * 64 + mi * 16 + quad * 4;
                    uint2 w = {pk2(acc[mi][ni][0] + bv, acc[mi][ni][1] + bv),
                               pk2(acc[mi][ni][2] + bv, acc[mi][ni][3] + bv)};
                    *(uint2*)(Vt + ((size_t)h * 64 + d) * (size_t)M_ + mrow) = w;
                }
            }
        } else {                           // wsel3: hq/vq -> Q96, scaled (3 tiles)
#pragma unroll
            for (int ni = 0; ni < 4; ++ni) {
                int n = n0 + wn * 64 + ni * 16 + lq;
                float bv = bias[n];
                int j = n - 3072;
                int h = j / 24, r = j - h * 24;
                int col = h * 96 + (r < 12 ? 64 + r : 68 + r);
#pragma unroll
                for (int mi = 0; mi < 4; ++mi) {
                    int mrow = m0 + wm * 64 + mi * 16 + quad * 4;
#pragma unroll
                    for (int rr = 0; rr < 4; ++rr)
                        Qb[(size_t)(mrow + rr) * QROW_ + col] =
                            f2bf((acc[mi][ni][rr] + bv) * QSCALE_);
                }
            }
        }
    } else {
#pragma unroll
        for (int ni = 0; ni < 4; ++ni) {
            int n = n0 + wn * 64 + ni * 16 + lq;
            float bv = bias[n];
#pragma unroll
            for (int mi = 0; mi < 4; ++mi) {
                int mrow = m0 + wm * 64 + mi * 16 + quad * 4;
#pragma unroll
                for (int rr = 0; rr < 4; ++rr)
                    Cf[(size_t)(mrow + rr) * 1024 + n] = acc[mi][ni][rr] + bv;
            }
        }
    }
}

// ---------------------------------------------------------------- attention
// R18: 4 barrier domains/CU. Block: one (b,h), 64 q, 256 thr (4 waves x
// 16 q). 32 K-tiles of 64 keys. LDS 40960: bufs @0/@20480 (20KB: K seg0
// [64k][128B] @0 pos c^(key&7); K seg1 [64k][64B] @8192 pos c^((key>>1)&3);
// V [64d][128B] @12288 pos c^(d&7)). Q direct global->VGPR.
// Staging: 5 slots/wave (ts = wv, wv+4, wv+8, wv+12, wv+16). kt-loop
// unrolled x2 (literal parity offsets). P in-register (permlane swaps).
// l via ones-MFMA: ol=mfma(pA,ones,ol) -> epilogue invr[r]=1/ol[r] in-lane.
#define ATQ_ 64

__global__ __launch_bounds__(256, 4) void attn_kernel(
    const unsigned short* __restrict__ Q96, const unsigned short* __restrict__ K96,
    const unsigned short* __restrict__ Vtg, unsigned short* __restrict__ ctxb)
{
    extern __shared__ __align__(16) unsigned char smem[];
    const int tid = threadIdx.x;
    const int wv = tid >> 6, lane = tid & 63;   // wv 0..3
    const int lq = lane & 15, quad = lane >> 4;
    const int bh = blockIdx.x;
    const int b = bh >> 4, h = bh & 15;
    const int q0 = blockIdx.y * ATQ_;
    const int lr = lane >> 3;                   // 128B-row staging: row-in-KB
    const int g = (lane & 7) ^ lr;              // source chunk
    const int g4 = (lane & 3) ^ ((lane >> 3) & 3);  // 64B-row staging chunk

    // ---- staging: 5 slots/wave: ts = {wv, wv+4, wv+8, wv+12, wv+16}
    const unsigned short* sp[5];
    unsigned inc[5], ld[5];
    {
        int ts[5] = {wv, wv + 4, wv + 8, wv + 12, wv + 16};
#pragma unroll
        for (int i = 0; i < 5; ++i) {
            int tt = ts[i];
            if (tt < 8) {
                sp[i] = K96 + (size_t)(b * S_ + tt * 8 + lr) * QROW_ + h * 96 + g * 8;
                inc[i] = 64 * QROW_;  ld[i] = tt * 1024;
            } else if (tt < 12) {
                int rr = (tt - 8) * 16 + (lane >> 2);
                sp[i] = K96 + (size_t)(b * S_ + rr) * QROW_ + h * 96 + 64 + g4 * 8;
                inc[i] = 64 * QROW_;  ld[i] = 8192 + (tt - 8) * 1024;
            } else {
                sp[i] = Vtg + (size_t)(h * 64 + (tt - 12) * 8 + lr) * (size_t)M_
                        + b * S_ + g * 8;
                inc[i] = 64;          ld[i] = 12288 + (tt - 12) * 1024;
            }
            inc[i] = __builtin_amdgcn_readfirstlane(inc[i]);
            ld[i] = __builtin_amdgcn_readfirstlane(ld[i]);
        }
    }

    // ---- Q direct global->VGPR: qf[ds] covers d = ds*32 + quad*8 ..+7
    s16x8 qf[3];
    {
        const unsigned short* qp = Q96 + (size_t)(b * S_ + q0 + wv * 16 + lq) * QROW_
                                   + h * 96 + quad * 8;
#pragma unroll
        for (int ds = 0; ds < 3; ++ds)
            qf[ds] = *(const s16x8*)(qp + ds * 32);
    }

    // ---- loop-invariant LDS read pointers
    const unsigned char* kp[4][3];
#pragma unroll
    for (int ka = 0; ka < 4; ++ka) {
        int key = ka * 16 + lq;
#pragma unroll
        for (int ds = 0; ds < 3; ++ds) {
            kp[ka][ds] = (ds < 2)
                ? smem + key * 128 + (((ds * 4 + quad) ^ (key & 7)) * 16)
                : smem + 8192 + key * 64 + ((quad ^ ((key >> 1) & 3)) * 16);
        }
    }
    const unsigned char* vp[2][4];
#pragma unroll
    for (int kk = 0; kk < 2; ++kk)
#pragma unroll
        for (int ni = 0; ni < 4; ++ni) {
            int d = ni * 16 + lq;
            vp[kk][ni] = smem + 12288 + d * 128 + (((kk * 4 + quad) ^ (d & 7)) * 16);
        }

    // ones B-frag (bf16 1.0) for l = P @ ones via MFMA
    s16x8 ones;
#pragma unroll
    for (int j = 0; j < 8; ++j) ones[j] = (short)0x3f80;

    f32x4 o[4] = {};
    f32x4 ol = {};

#define ASTAGE(DSTOFF) do { \
    _Pragma("unroll") \
    for (int i = 0; i < 5; ++i) { \
        GLDS16(sp[i], smem + (ld[i] + (DSTOFF))); \
        sp[i] += inc[i]; \
    } \
} while (0)

#define ATILE(CUROFF) do { \
    f32x4 st[4] = {}; \
    _Pragma("unroll") \
    for (int ka = 0; ka < 4; ++ka) { \
        __builtin_amdgcn_s_setprio(1); \
        _Pragma("unroll") \
        for (int ds = 0; ds < 3; ++ds) { \
            s16x8 kf = *(const s16x8*)(kp[ka][ds] + (CUROFF)); \
            st[ka] = __builtin_amdgcn_mfma_f32_16x16x32_bf16( \
                kf, qf[ds], st[ka], 0, 0, 0); \
        } \
        __builtin_amdgcn_s_setprio(0); \
    } \
    unsigned w0[4], w1[4]; \
    _Pragma("unroll") \
    for (int ka = 0; ka < 4; ++ka) { \
        float p0 = EXP2(st[ka][0]); \
        float p1 = EXP2(st[ka][1]); \
        float p2 = EXP2(st[ka][2]); \
        float p3 = EXP2(st[ka][3]); \
        w0[ka] = pk2(p0, p1); \
        w1[ka] = pk2(p2, p3); \
    } \
    __builtin_amdgcn_s_setprio(1); \
    _Pragma("unroll") \
    for (int kk = 0; kk < 2; ++kk) { \
        unsigned x0 = w0[kk * 2], y0 = w0[kk * 2 + 1]; \
        unsigned x1 = w1[kk * 2], y1 = w1[kk * 2 + 1]; \
        asm volatile("v_permlane32_swap_b32 %0, %1" : "+v"(x0), "+v"(y0)); \
        asm volatile("v_permlane16_swap_b32 %0, %1" : "+v"(x0), "+v"(y0)); \
        asm volatile("v_permlane32_swap_b32 %0, %1" : "+v"(x1), "+v"(y1)); \
        asm volatile("v_permlane16_swap_b32 %0, %1" : "+v"(x1), "+v"(y1)); \
        unsigned u4[4] = {x0, x1, y0, y1}; \
        s16x8 pA; \
        __builtin_memcpy(&pA, u4, 16); \
        _Pragma("unroll") \
        for (int ni = 0; ni < 4; ++ni) { \
            s16x8 vB = *(const s16x8*)(vp[kk][ni] + (CUROFF)); \
            o[ni] = __builtin_amdgcn_mfma_f32_16x16x32_bf16( \
                pA, vB, o[ni], 0, 0, 0); \
        } \
        ol = __builtin_amdgcn_mfma_f32_16x16x32_bf16(pA, ones, ol, 0, 0, 0); \
    } \
    __builtin_amdgcn_s_setprio(0); \
} while (0)

    ASTAGE(0);                      // prologue: kt=0 -> buf0
    for (int i2 = 0; i2 < 16; ++i2) {
        __syncthreads();
        ASTAGE(20480);              // kt=2*i2+1 -> buf1
        ATILE(0);                   // compute kt=2*i2
        __syncthreads();
        if (i2 < 15) ASTAGE(0);     // kt=2*i2+2 -> buf0
        ATILE(20480);               // compute kt=2*i2+1
    }
#undef ASTAGE
#undef ATILE

    // ---- epilogue: ol[r] = l for q-row quad*4+r (same row as o[ni][r])
    {
#pragma unroll
        for (int r = 0; r < 4; ++r) {
            float iv = 1.0f / ol[r];
            int row = q0 + wv * 16 + quad * 4 + r;
#pragma unroll
            for (int ni = 0; ni < 4; ++ni)
                ctxb[(size_t)(b * S_ + row) * 1024 + h * 64 + ni * 16 + lq] =
                    f2bf(o[ni][r] * iv);
        }
    }
}

// ---------------------------------------------------------------- launch
extern "C" void kernel_launch(void* const* d_in, const int* in_sizes, int n_in,
                              void* d_out, int out_size, void* d_ws, size_t ws_size,
                              hipStream_t stream)
{
    const float* x        = (const float*)d_in[0];
    const float* pitch_pc = (const float*)d_in[1];
    const float* bass_pc  = (const float*)d_in[2];
    const float* Wpq = (const float*)d_in[3];   const float* bpq = (const float*)d_in[4];
    const float* Whq = (const float*)d_in[5];   const float* bhq = (const float*)d_in[6];
    const float* Wvq = (const float*)d_in[7];   const float* bvq = (const float*)d_in[8];
    const float* Wk  = (const float*)d_in[9];   const float* bk  = (const float*)d_in[10];
    const float* Wv  = (const float*)d_in[11];  const float* bv  = (const float*)d_in[12];
    const float* Wo  = (const float*)d_in[13];  const float* bo  = (const float*)d_in[14];
    const float* Wc  = (const float*)d_in[15];  const float* bc  = (const float*)d_in[16];
    const float* Wb  = (const float*)d_in[17];  const float* bb  = (const float*)d_in[18];
    (void)bc; (void)bb;   // key-independent score shifts: softmax-invariant

    char* ws = (char*)d_ws;
    unsigned short* xb    = (unsigned short*)(ws);                     // 8 MB @0
    unsigned short* W3t   = (unsigned short*)(ws + 8388608);           // 6 MB (Bt rows 0..3071)
    unsigned short* Whcvt = (unsigned short*)(ws + 14680064);          // 768 KB (rows 3072..3455)
    unsigned short* Wot   = (unsigned short*)(ws + 15466496);          // 2 MB
    float*          bias5 = (float*)         (ws + 17563648);          // 13.5 KB (3456)
    unsigned short* Q96   = (unsigned short*)(ws + 17577472);          // 12.6 MB
    unsigned short* K96   = (unsigned short*)(ws + 30160384);          // 12.6 MB
    unsigned short* Vtg   = (unsigned short*)(ws + 42743296);          // 8 MB
    unsigned short* ctxb  = (unsigned short*)(ws + 51131904);          // 8 MB

    PrepArgs pa;
    pa.x = x; pa.pitch_pc = pitch_pc; pa.bass_pc = bass_pc;
    pa.Wc = Wc; pa.Wb = Wb;
    pa.Whq = Whq; pa.bhq = bhq; pa.Wvq = Wvq; pa.bvq = bvq;
    pa.wsrc[0] = Wpq; pa.wsrc[1] = Wk; pa.wsrc[2] = Wv; pa.wsrc[3] = Wo;
    pa.wdst[0] = W3t;
    pa.wdst[1] = W3t + (size_t)1024 * 1024;
    pa.wdst[2] = W3t + (size_t)2048 * 1024;
    pa.wdst[3] = Wot;
    pa.bsrc[0] = bpq; pa.bsrc[1] = bk; pa.bsrc[2] = bv;
    pa.bias5 = bias5; pa.Whcvt = Whcvt;
    pa.xb = xb; pa.Q96 = Q96; pa.K96 = K96;

    cvt_kernel<<<dim3(4096), 256, 0, stream>>>(pa);
    wtrans_kernel<<<dim3(1024), 256, 0, stream>>>(pa);
    misc_kernel<<<dim3(12 + 384 + 256), 256, 0, stream>>>(pa);

    gemm_k<0><<<dim3(27, 32), 256, 0, stream>>>(xb, W3t, bias5, Q96, K96, Vtg, nullptr);

    attn_kernel<<<dim3(B_ * H_, S_ / ATQ_), 256, 40960, stream>>>(Q96, K96, Vtg, ctxb);

    gemm_k<1><<<dim3(8, 32), 256, 0, stream>>>(ctxb, Wot, bo, nullptr, nullptr, nullptr,
                                               (float*)d_out);
}

// Round 13
// 251.248 us; speedup vs baseline: 1.0413x; 1.0413x over previous
//
#include <hip/hip_runtime.h>
#include <hip/hip_bf16.h>
#include <math.h>

// ChordAwareTransformer bf16-MFMA pipeline, round 19.
// R19 = R17 revert (R18's 4-domain attn was flat-to-worse; barrier-domain
// theory twice-falsified R11/R18) + two VALU-relief tweaks on R17's attn:
//  * ones-MFMA l (from R18, numerics validated): ol=mfma(pA,ones,ol) on the
//    31%-busy MFMA pipe replaces 12-16 VALU adds/kt + 6 epilogue shfls.
//    ol[r] and o[ni][r] share row=quad*4+r -> invr in-lane.
//  * s_setprio removed: attn waves are barrier-locked (m190: setprio is
//    null-to-negative in lockstep schedules); VALU is the critical pipe.
// R17: unrolled x2 K-loops, literal buffer offsets, precomputed LDS ptrs;
// R16: prep split; R15: P-in-register permlane swaps; R14: gemm0 XCD
// swizzle + transpose epilogue; R13: rank-12 d=96 refactor.
// MFMA layouts (HW-verified): A[m=lane&15][k=quad*8+j], B[k][n=lane&15],
// C/D row=quad*4+reg, col=lane&15.

#define D_    1024
#define H_    16
#define B_    2
#define S_    2048
#define M_    (B_*S_)
#define QROW_ 1536          // Q96/K96 row stride in shorts (16 heads * 96)

#define QSCALE_ (1.44269504f / 24.0f)   // log2e * (1/sqrt(64)) / 3

#if __has_builtin(__builtin_amdgcn_exp2f)
#define EXP2(x) __builtin_amdgcn_exp2f(x)
#else
#define EXP2(x) exp2f(x)
#endif

typedef __attribute__((ext_vector_type(8))) short s16x8;
typedef __attribute__((ext_vector_type(4))) float f32x4;

__device__ __forceinline__ unsigned short f2bf(float f) {
    unsigned u = __builtin_bit_cast(unsigned, f);
    u += 0x7fff + ((u >> 16) & 1);          // RNE
    return (unsigned short)(u >> 16);
}
__device__ __forceinline__ unsigned pk2(float a, float b) {
    __hip_bfloat162 h = __float22bfloat162_rn(float2{a, b});
    unsigned r;
    __builtin_memcpy(&r, &h, 4);
    return r;
}

#define GLDS16(gp, lp) \
    __builtin_amdgcn_global_load_lds((const __attribute__((address_space(1))) void*)(gp), \
                                     (__attribute__((address_space(3))) void*)(lp), 16, 0, 0)

// ---------------------------------------------------------------- prep kernels
struct PrepArgs {
    const float* x;
    const float* pitch_pc; const float* bass_pc;
    const float* Wc; const float* Wb;
    const float* Whq; const float* bhq;
    const float* Wvq; const float* bvq;
    const float* wsrc[4]; unsigned short* wdst[4];   // Wpq,Wk,Wv,Wo
    const float* bsrc[3]; float* bias5;              // bpq,bk,bv
    unsigned short* Whcvt;                           // 384 x 1024 (Bt rows 3072..3455)
    unsigned short* xb; unsigned short* Q96; unsigned short* K96;
};

// ---- cvt_x: fp32 -> bf16, pure streaming copy (low VGPR, no LDS)
__global__ __launch_bounds__(256) void cvt_kernel(PrepArgs a) {
    int i = (blockIdx.x * 256 + threadIdx.x) * 4;
    float4 v = *(const float4*)(a.x + i);
    uint2 o = {pk2(v.x, v.y), pk2(v.z, v.w)};
    *(uint2*)(a.xb + i) = o;
}

// ---- wtrans: 4 weights, 64x64 transpose tiles via LDS
__global__ __launch_bounds__(256) void wtrans_kernel(PrepArgs a) {
    __shared__ unsigned short t[64][72];
    int bx = blockIdx.x;
    const int tid = threadIdx.x;
    int z = bx >> 8, rem = bx & 255;
    const float* src = a.wsrc[z];
    unsigned short* dst = a.wdst[z];
    int k0 = (rem >> 4) * 64, n0 = (rem & 15) * 64;
    int r = tid >> 2, c0 = (tid & 3) * 16;
#pragma unroll
    for (int i = 0; i < 4; ++i) {
        float4 v = *(const float4*)(src + (size_t)(k0 + r) * 1024 + n0 + c0 + i * 4);
        ushort4 o = {f2bf(v.x), f2bf(v.y), f2bf(v.z), f2bf(v.w)};
        *(ushort4*)&t[r][c0 + i * 4] = o;
    }
    __syncthreads();
#pragma unroll
    for (int i = 0; i < 4; ++i) {
        ushort4 o = {t[c0 + i*4 + 0][r], t[c0 + i*4 + 1][r],
                     t[c0 + i*4 + 2][r], t[c0 + i*4 + 3][r]};
        *(ushort4*)(dst + (size_t)(n0 + r) * 1024 + k0 + c0 + i * 4) = o;
    }
}

// ---- misc: bpack (12) + fold (384, vectorized) + pcpack (256)
__global__ __launch_bounds__(256) void misc_kernel(PrepArgs a) {
    int bx = blockIdx.x;
    const int tid = threadIdx.x;

    if (bx < 12) {                         // ---- bpack (bpq,bk,bv)
        int i = bx * 256 + tid;
        a.bias5[i] = a.bsrc[i >> 10][i & 1023];
        return;
    }
    bx -= 12;
    if (bx < 384) {                        // ---- fold: Whcvt row j (Bt layout)
        int j = bx;
        int h = j / 24, r = j - h * 24;
        const float* src = (r < 12) ? a.Whq : a.Wvq;
        const float* pcw = (r < 12) ? a.Wc  : a.Wb;
        const float* bsr = (r < 12) ? a.bhq : a.bvq;
        int i = (r < 12) ? r : r - 12;
        int hb = h * 64;
        const float4* p4 = (const float4*)(pcw + (size_t)i * 1024 + hb);
        float4 pv[16];
#pragma unroll
        for (int d = 0; d < 16; ++d) pv[d] = p4[d];
#pragma unroll
        for (int ro = 0; ro < 4; ++ro) {
            int row = tid + ro * 256;
            const float4* s4 = (const float4*)(src + (size_t)row * 1024 + hb);
            float a0 = 0.f, a1 = 0.f, a2 = 0.f, a3 = 0.f;
#pragma unroll
            for (int d = 0; d < 16; d += 4) {
                float4 v0 = s4[d], v1 = s4[d+1], v2 = s4[d+2], v3 = s4[d+3];
                a0 = fmaf(v0.x, pv[d].x, fmaf(v0.y, pv[d].y,
                     fmaf(v0.z, pv[d].z, fmaf(v0.w, pv[d].w, a0))));
                a1 = fmaf(v1.x, pv[d+1].x, fmaf(v1.y, pv[d+1].y,
                     fmaf(v1.z, pv[d+1].z, fmaf(v1.w, pv[d+1].w, a1))));
                a2 = fmaf(v2.x, pv[d+2].x, fmaf(v2.y, pv[d+2].y,
                     fmaf(v2.z, pv[d+2].z, fmaf(v2.w, pv[d+2].w, a2))));
                a3 = fmaf(v3.x, pv[d+3].x, fmaf(v3.y, pv[d+3].y,
                     fmaf(v3.z, pv[d+3].z, fmaf(v3.w, pv[d+3].w, a3))));
            }
            a.Whcvt[(size_t)j * 1024 + row] = f2bf((a0 + a1) + (a2 + a3));
        }
        if (tid == 0) {
            float bacc = 0.f;
            for (int d = 0; d < 64; ++d)
                bacc = fmaf(bsr[hb + d], pcw[i * 1024 + hb + d], bacc);
            a.bias5[3072 + j] = bacc;
        }
        return;
    }
    bx -= 384;
    {                                      // ---- pcpack: K96 pc cols + pads; Q96 pads
        int idx = bx * 256 + tid;          // 65536 = M*H
        int m = idx >> 4, h = idx & 15;
        int s = m & (S_ - 1);
        unsigned short buf[32];
#pragma unroll
        for (int i = 0; i < 12; ++i) buf[i] = f2bf(a.pitch_pc[s * 12 + i]);
        buf[12] = buf[13] = buf[14] = buf[15] = 0;
#pragma unroll
        for (int i = 0; i < 12; ++i) buf[16 + i] = f2bf(a.bass_pc[s * 12 + i]);
        buf[28] = buf[29] = buf[30] = buf[31] = 0;
        unsigned short* kd = a.K96 + (size_t)m * QROW_ + h * 96 + 64;
#pragma unroll
        for (int i = 0; i < 4; ++i)
            *(uint4*)(kd + i * 8) = *(uint4*)&buf[i * 8];
        unsigned short* qd = a.Q96 + (size_t)m * QROW_ + h * 96 + 64;
        uint2 z = {0u, 0u};
        *(uint2*)(qd + 12) = z;            // cols 76..79
        *(uint2*)(qd + 28) = z;            // cols 92..95
    }
}

// ---------------------------------------------------------------- MFMA GEMM
// C[M x N] = A[M x 1024] @ Bt^T + bias.  BK=32, double-buffered, one barrier
// per K-tile; kt-loop unrolled x2 (literal buffer offsets 0/16384).
// XCD-swizzled block ids (nwg%8==0 both modes).
// MODE 0 (N=3456): wsel0 pitch_q*QS -> Q96; wsel1 k -> K96 (both via LDS
//   transpose epilogue, 128B row stores); wsel2 v -> Vt^T (uint2, coalesced);
//   wsel3 hq/vq*QS -> Q96 cols 64+/68+ (scalar, 3 tiles only).
// MODE 1: N=1024, fp32 out.
template<int MODE>
__global__ __launch_bounds__(256) void gemm_k(
    const unsigned short* __restrict__ A, const unsigned short* __restrict__ Bt,
    const float* __restrict__ bias, unsigned short* __restrict__ Qb,
    unsigned short* __restrict__ Kb, unsigned short* __restrict__ Vt,
    float* __restrict__ Cf)
{
    __shared__ __align__(16) unsigned char lds[32768];
    const int tid = threadIdx.x;
    const int wv = tid >> 6, lane = tid & 63;
    const int lq = lane & 15, quad = lane >> 4;
    const int wm = wv >> 1, wn = wv & 1;

    // XCD-aware swizzle: each XCD gets a contiguous chunk (nwg % 8 == 0)
    const unsigned bid = blockIdx.y * gridDim.x + blockIdx.x;
    const unsigned cpx = (gridDim.x * gridDim.y) >> 3;
    const unsigned swz = (bid & 7) * cpx + (bid >> 3);
    const int m0 = (int)(swz / gridDim.x) * 128;
    const int n0 = (int)(swz % gridDim.x) * 128;

    const int sr = lane >> 2;
    const int sc = (lane & 3) ^ ((lane >> 3) & 3);

    // staging source pointers (advance += 32 shorts per staged kt)
    const unsigned short* Asrc[2];
    const unsigned short* Bsrc[2];
    unsigned dla[2], dlb[2];
#pragma unroll
    for (int j = 0; j < 2; ++j) {
        int seg = wv * 2 + j;
        Asrc[j] = A + (size_t)(m0 + seg * 16 + sr) * 1024 + sc * 8;
        Bsrc[j] = Bt + (size_t)(n0 + seg * 16 + sr) * 1024 + sc * 8;
        dla[j] = seg * 1024;
        dlb[j] = 8192 + seg * 1024;
    }

    // loop-invariant LDS read pointers
    const unsigned char* ap[4];
    const unsigned char* bp4[4];
#pragma unroll
    for (int mi = 0; mi < 4; ++mi) {
        int row = wm * 64 + mi * 16 + lq;
        ap[mi] = lds + row * 64 + ((quad ^ ((row >> 1) & 3)) * 16);
    }
#pragma unroll
    for (int ni = 0; ni < 4; ++ni) {
        int row = wn * 64 + ni * 16 + lq;
        bp4[ni] = lds + 8192 + row * 64 + ((quad ^ ((row >> 1) & 3)) * 16);
    }

    f32x4 acc[4][4] = {};

#define GSTAGE(DSTOFF) do { \
    _Pragma("unroll") \
    for (int j = 0; j < 2; ++j) { \
        GLDS16(Asrc[j], lds + (dla[j] + (DSTOFF))); Asrc[j] += 32; \
        GLDS16(Bsrc[j], lds + (dlb[j] + (DSTOFF))); Bsrc[j] += 32; \
    } \
} while (0)

#define GTILE(CUROFF) do { \
    s16x8 aF[4], bF[4]; \
    _Pragma("unroll") \
    for (int mi = 0; mi < 4; ++mi) aF[mi] = *(const s16x8*)(ap[mi] + (CUROFF)); \
    _Pragma("unroll") \
    for (int ni = 0; ni < 4; ++ni) bF[ni] = *(const s16x8*)(bp4[ni] + (CUROFF)); \
    _Pragma("unroll") \
    for (int mi = 0; mi < 4; ++mi) \
        _Pragma("unroll") \
        for (int ni = 0; ni < 4; ++ni) \
            acc[mi][ni] = __builtin_amdgcn_mfma_f32_16x16x32_bf16( \
                aF[mi], bF[ni], acc[mi][ni], 0, 0, 0); \
} while (0)

    GSTAGE(0);                     // prologue: kt=0 -> buf0
    for (int i2 = 0; i2 < 16; ++i2) {
        __syncthreads();
        GSTAGE(16384);             // kt=2*i2+1 -> buf1
        GTILE(0);                  // compute kt=2*i2
        __syncthreads();
        if (i2 < 15) GSTAGE(0);    // kt=2*i2+2 -> buf0
        GTILE(16384);              // compute kt=2*i2+1
    }
#undef GSTAGE
#undef GTILE

    if (MODE == 0) {
        const int wsel = n0 >> 10;
        if (wsel <= 1) {
            // ---- LDS-transpose epilogue: C tile [128 m][128 n] bf16 in lds,
            // chunk pos = (col>>3) ^ (row&7); then 128B-contiguous row stores.
            const float sc2 = (wsel == 0) ? QSCALE_ : 1.0f;
            unsigned short* lt = (unsigned short*)lds;
            __syncthreads();   // all waves done reading staging bufs
#pragma unroll
            for (int ni = 0; ni < 4; ++ni) {
                int col = wn * 64 + ni * 16 + lq;
                float bv = bias[n0 + col];
#pragma unroll
                for (int mi = 0; mi < 4; ++mi) {
#pragma unroll
                    for (int r = 0; r < 4; ++r) {
                        int row = wm * 64 + mi * 16 + quad * 4 + r;
                        int pos = (col >> 3) ^ (row & 7);
                        lt[row * 128 + pos * 8 + (col & 7)] =
                            f2bf((acc[mi][ni][r] + bv) * sc2);
                    }
                }
            }
            __syncthreads();
            const int row = tid >> 1, seg = tid & 1;
            const int nl0 = n0 & 1023;
            unsigned short* dstp = (wsel == 0) ? Qb : Kb;
            unsigned short* dbase = dstp + (size_t)(m0 + row) * QROW_
                                    + (nl0 >> 6) * 96 + seg * 96;
#pragma unroll
            for (int i = 0; i < 8; ++i) {
                int c = seg * 8 + i;
                int pos = c ^ (row & 7);
                *(uint4*)(dbase + i * 8) = *(const uint4*)(lt + row * 128 + pos * 8);
            }
        } else if (wsel == 2) {            // v -> Vt^T (bf16 pairs, coalesced on m)
#pragma unroll
            for (int ni = 0; ni < 4; ++ni) {
                int n = n0 + wn * 64 + ni * 16 + lq;
                float bv = bias[n];
                int nl = n - 2048, h = nl >> 6, d = nl & 63;
#pragma unroll
                for (int mi = 0; mi < 4; ++mi) {
                    int mrow = m0 + wm * 64 + mi * 16 + quad * 4;
                    uint2 w = {pk2(acc[mi][ni][0] + bv, acc[mi][ni][1] + bv),
                               pk2(acc[mi][ni][2] + bv, acc[mi][ni][3] + bv)};
                    *(uint2*)(Vt + ((size_t)h * 64 + d) * (size_t)M_ + mrow) = w;
                }
            }
        } else {                           // wsel3: hq/vq -> Q96, scaled (3 tiles)
#pragma unroll
            for (int ni = 0; ni < 4; ++ni) {
                int n = n0 + wn * 64 + ni * 16 + lq;
                float bv = bias[n];
                int j = n - 3072;
                int h = j / 24, r = j - h * 24;
                int col = h * 96 + (r < 12 ? 64 + r : 68 + r);
#pragma unroll
                for (int mi = 0; mi < 4; ++mi) {
                    int mrow = m0 + wm * 64 + mi * 16 + quad * 4;
#pragma unroll
                    for (int rr = 0; rr < 4; ++rr)
                        Qb[(size_t)(mrow + rr) * QROW_ + col] =
                            f2bf((acc[mi][ni][rr] + bv) * QSCALE_);
                }
            }
        }
    } else {
#pragma unroll
        for (int ni = 0; ni < 4; ++ni) {
            int n = n0 + wn * 64 + ni * 16 + lq;
            float bv = bias[n];
#pragma unroll
            for (int mi = 0; mi < 4; ++mi) {
                int mrow = m0 + wm * 64 + mi * 16 + quad * 4;
#pragma unroll
                for (int rr = 0; rr < 4; ++rr)
                    Cf[(size_t)(mrow + rr) * 1024 + n] = acc[mi][ni][rr] + bv;
            }
        }
    }
}

// ---------------------------------------------------------------- attention
// R17 structure (proven 57.4us): one (b,h), 128 q, 512 thr (8 waves x 16 q),
// 32 K-tiles of 64 keys, kt-loop unrolled x2 with literal parity offsets.
// LDS 40960: bufs @0/@20480 (20KB: K seg0 [64k][128B] @0 pos c^(key&7);
// K seg1 [64k][64B] @8192 pos c^((key>>1)&3); V [64d][128B] @12288 pos
// c^(d&7)). Q direct global->VGPR. P in-register (permlane swaps).
// R19: no s_setprio (lockstep waves, m190); l via ones-MFMA (ol[r] row
// matches o[ni][r] row = quad*4+r) -> in-lane normalize, no shfls.
#define ATQ_ 128

__global__ __launch_bounds__(512, 2) void attn_kernel(
    const unsigned short* __restrict__ Q96, const unsigned short* __restrict__ K96,
    const unsigned short* __restrict__ Vtg, unsigned short* __restrict__ ctxb)
{
    extern __shared__ __align__(16) unsigned char smem[];
    const int tid = threadIdx.x;
    const int wv = tid >> 6, lane = tid & 63;   // wv 0..7
    const int lq = lane & 15, quad = lane >> 4;
    const int bh = blockIdx.x;
    const int b = bh >> 4, h = bh & 15;
    const int q0 = blockIdx.y * ATQ_;
    const int lr = lane >> 3;                   // 128B-row staging: row-in-KB
    const int g = (lane & 7) ^ lr;              // source chunk
    const int g4 = (lane & 3) ^ ((lane >> 3) & 3);  // 64B-row staging chunk

    // ---- staging slots: A=wv (K seg0), B=wv+8, C=wv+16 (wv<4 only)
    const unsigned short* sp[3];
    unsigned inc[3], ld[3];
    const bool useC = (wv < 4);
    {
        int ts[3] = {wv, wv + 8, useC ? wv + 16 : 12};
#pragma unroll
        for (int i = 0; i < 3; ++i) {
            int tt = ts[i];
            if (tt < 8) {
                sp[i] = K96 + (size_t)(b * S_ + tt * 8 + lr) * QROW_ + h * 96 + g * 8;
                inc[i] = 64 * QROW_;  ld[i] = tt * 1024;
            } else if (tt < 12) {
                int rr = (tt - 8) * 16 + (lane >> 2);
                sp[i] = K96 + (size_t)(b * S_ + rr) * QROW_ + h * 96 + 64 + g4 * 8;
                inc[i] = 64 * QROW_;  ld[i] = 8192 + (tt - 8) * 1024;
            } else {
                sp[i] = Vtg + (size_t)(h * 64 + (tt - 12) * 8 + lr) * (size_t)M_
                        + b * S_ + g * 8;
                inc[i] = 64;          ld[i] = 12288 + (tt - 12) * 1024;
            }
            inc[i] = __builtin_amdgcn_readfirstlane(inc[i]);
            ld[i] = __builtin_amdgcn_readfirstlane(ld[i]);
        }
    }

    // ---- Q direct global->VGPR: qf[ds] covers d = ds*32 + quad*8 ..+7
    s16x8 qf[3];
    {
        const unsigned short* qp = Q96 + (size_t)(b * S_ + q0 + wv * 16 + lq) * QROW_
                                   + h * 96 + quad * 8;
#pragma unroll
        for (int ds = 0; ds < 3; ++ds)
            qf[ds] = *(const s16x8*)(qp + ds * 32);
    }

    // ---- loop-invariant LDS read pointers
    const unsigned char* kp[4][3];
#pragma unroll
    for (int ka = 0; ka < 4; ++ka) {
        int key = ka * 16 + lq;
#pragma unroll
        for (int ds = 0; ds < 3; ++ds) {
            kp[ka][ds] = (ds < 2)
                ? smem + key * 128 + (((ds * 4 + quad) ^ (key & 7)) * 16)
                : smem + 8192 + key * 64 + ((quad ^ ((key >> 1) & 3)) * 16);
        }
    }
    const unsigned char* vp[2][4];
#pragma unroll
    for (int kk = 0; kk < 2; ++kk)
#pragma unroll
        for (int ni = 0; ni < 4; ++ni) {
            int d = ni * 16 + lq;
            vp[kk][ni] = smem + 12288 + d * 128 + (((kk * 4 + quad) ^ (d & 7)) * 16);
        }

    // ones B-frag (bf16 1.0) for l = P @ ones via MFMA
    s16x8 ones;
#pragma unroll
    for (int j = 0; j < 8; ++j) ones[j] = (short)0x3f80;

    f32x4 o[4] = {};
    f32x4 ol = {};

#define ASTAGE(DSTOFF) do { \
    _Pragma("unroll") \
    for (int i = 0; i < 3; ++i) \
        if (i < 2 || useC) { \
            GLDS16(sp[i], smem + (ld[i] + (DSTOFF))); \
            sp[i] += inc[i]; \
        } \
} while (0)

#define ATILE(CUROFF) do { \
    f32x4 st[4] = {}; \
    _Pragma("unroll") \
    for (int ka = 0; ka < 4; ++ka) { \
        _Pragma("unroll") \
        for (int ds = 0; ds < 3; ++ds) { \
            s16x8 kf = *(const s16x8*)(kp[ka][ds] + (CUROFF)); \
            st[ka] = __builtin_amdgcn_mfma_f32_16x16x32_bf16( \
                kf, qf[ds], st[ka], 0, 0, 0); \
        } \
    } \
    unsigned w0[4], w1[4]; \
    _Pragma("unroll") \
    for (int ka = 0; ka < 4; ++ka) { \
        float p0 = EXP2(st[ka][0]); \
        float p1 = EXP2(st[ka][1]); \
        float p2 = EXP2(st[ka][2]); \
        float p3 = EXP2(st[ka][3]); \
        w0[ka] = pk2(p0, p1); \
        w1[ka] = pk2(p2, p3); \
    } \
    _Pragma("unroll") \
    for (int kk = 0; kk < 2; ++kk) { \
        unsigned x0 = w0[kk * 2], y0 = w0[kk * 2 + 1]; \
        unsigned x1 = w1[kk * 2], y1 = w1[kk * 2 + 1]; \
        asm volatile("v_permlane32_swap_b32 %0, %1" : "+v"(x0), "+v"(y0)); \
        asm volatile("v_permlane16_swap_b32 %0, %1" : "+v"(x0), "+v"(y0)); \
        asm volatile("v_permlane32_swap_b32 %0, %1" : "+v"(x1), "+v"(y1)); \
        asm volatile("v_permlane16_swap_b32 %0, %1" : "+v"(x1), "+v"(y1)); \
        unsigned u4[4] = {x0, x1, y0, y1}; \
        s16x8 pA; \
        __builtin_memcpy(&pA, u4, 16); \
        _Pragma("unroll") \
        for (int ni = 0; ni < 4; ++ni) { \
            s16x8 vB = *(const s16x8*)(vp[kk][ni] + (CUROFF)); \
            o[ni] = __builtin_amdgcn_mfma_f32_16x16x32_bf16( \
                pA, vB, o[ni], 0, 0, 0); \
        } \
        ol = __builtin_amdgcn_mfma_f32_16x16x32_bf16(pA, ones, ol, 0, 0, 0); \
    } \
} while (0)

    ASTAGE(0);                      // prologue: kt=0 -> buf0
    for (int i2 = 0; i2 < 16; ++i2) {
        __syncthreads();
        ASTAGE(20480);              // kt=2*i2+1 -> buf1
        ATILE(0);                   // compute kt=2*i2
        __syncthreads();
        if (i2 < 15) ASTAGE(0);     // kt=2*i2+2 -> buf0
        ATILE(20480);               // compute kt=2*i2+1
    }
#undef ASTAGE
#undef ATILE

    // ---- epilogue: ol[r] = l for q-row quad*4+r (same row as o[ni][r])
    {
#pragma unroll
        for (int r = 0; r < 4; ++r) {
            float iv = 1.0f / ol[r];
            int row = q0 + wv * 16 + quad * 4 + r;
#pragma unroll
            for (int ni = 0; ni < 4; ++ni)
                ctxb[(size_t)(b * S_ + row) * 1024 + h * 64 + ni * 16 + lq] =
                    f2bf(o[ni][r] * iv);
        }
    }
}

// ---------------------------------------------------------------- launch
extern "C" void kernel_launch(void* const* d_in, const int* in_sizes, int n_in,
                              void* d_out, int out_size, void* d_ws, size_t ws_size,
                              hipStream_t stream)
{
    const float* x        = (const float*)d_in[0];
    const float* pitch_pc = (const float*)d_in[1];
    const float* bass_pc  = (const float*)d_in[2];
    const float* Wpq = (const float*)d_in[3];   const float* bpq = (const float*)d_in[4];
    const float* Whq = (const float*)d_in[5];   const float* bhq = (const float*)d_in[6];
    const float* Wvq = (const float*)d_in[7];   const float* bvq = (const float*)d_in[8];
    const float* Wk  = (const float*)d_in[9];   const float* bk  = (const float*)d_in[10];
    const float* Wv  = (const float*)d_in[11];  const float* bv  = (const float*)d_in[12];
    const float* Wo  = (const float*)d_in[13];  const float* bo  = (const float*)d_in[14];
    const float* Wc  = (const float*)d_in[15];  const float* bc  = (const float*)d_in[16];
    const float* Wb  = (const float*)d_in[17];  const float* bb  = (const float*)d_in[18];
    (void)bc; (void)bb;   // key-independent score shifts: softmax-invariant

    char* ws = (char*)d_ws;
    unsigned short* xb    = (unsigned short*)(ws);                     // 8 MB @0
    unsigned short* W3t   = (unsigned short*)(ws + 8388608);           // 6 MB (Bt rows 0..3071)
    unsigned short* Whcvt = (unsigned short*)(ws + 14680064);          // 768 KB (rows 3072..3455)
    unsigned short* Wot   = (unsigned short*)(ws + 15466496);          // 2 MB
    float*          bias5 = (float*)         (ws + 17563648);          // 13.5 KB (3456)
    unsigned short* Q96   = (unsigned short*)(ws + 17577472);          // 12.6 MB
    unsigned short* K96   = (unsigned short*)(ws + 30160384);          // 12.6 MB
    unsigned short* Vtg   = (unsigned short*)(ws + 42743296);          // 8 MB
    unsigned short* ctxb  = (unsigned short*)(ws + 51131904);          // 8 MB

    PrepArgs pa;
    pa.x = x; pa.pitch_pc = pitch_pc; pa.bass_pc = bass_pc;
    pa.Wc = Wc; pa.Wb = Wb;
    pa.Whq = Whq; pa.bhq = bhq; pa.Wvq = Wvq; pa.bvq = bvq;
    pa.wsrc[0] = Wpq; pa.wsrc[1] = Wk; pa.wsrc[2] = Wv; pa.wsrc[3] = Wo;
    pa.wdst[0] = W3t;
    pa.wdst[1] = W3t + (size_t)1024 * 1024;
    pa.wdst[2] = W3t + (size_t)2048 * 1024;
    pa.wdst[3] = Wot;
    pa.bsrc[0] = bpq; pa.bsrc[1] = bk; pa.bsrc[2] = bv;
    pa.bias5 = bias5; pa.Whcvt = Whcvt;
    pa.xb = xb; pa.Q96 = Q96; pa.K96 = K96;

    cvt_kernel<<<dim3(4096), 256, 0, stream>>>(pa);
    wtrans_kernel<<<dim3(1024), 256, 0, stream>>>(pa);
    misc_kernel<<<dim3(12 + 384 + 256), 256, 0, stream>>>(pa);

    gemm_k<0><<<dim3(27, 32), 256, 0, stream>>>(xb, W3t, bias5, Q96, K96, Vtg, nullptr);

    attn_kernel<<<dim3(B_ * H_, S_ / ATQ_), 512, 40960, stream>>>(Q96, K96, Vtg, ctxb);

    gemm_k<1><<<dim3(8, 32), 256, 0, stream>>>(ctxb, Wot, bo, nullptr, nullptr, nullptr,
                                               (float*)d_out);
}